// Round 1
// baseline (742.410 us; speedup 1.0000x reference)
//
#include <hip/hip_runtime.h>

// Problem dims (fixed by setup_inputs)
#define BB 16
#define CR 1024
#define HWD 784     // 28*28
#define HW2 392     // HWD/2 (float2 units)
#define CS 256
#define SSZ 25
#define SP 28       // padded row length for kk/M/v
#define CI 512
#define CSPLIT 8    // c-chunks in energy (each 128)
#define CCHUNK 128
#define RCHUNK 32
#define KC 4
#define NBLK 1024   // 4 blocks/CU x 256 CUs -- all co-resident by __launch_bounds__(256,4)

// Workspace layout (floats). Same as 8-kernel version; Ep aliases kk|P (dead by P5).
#define OFF_POOLED 0          // [B][CS][S]         = 102400
#define OFF_VP     102400     // [B][CR][SP]        = 458752
#define OFF_MP     561152     // [B][CR][SP]        = 458752
#define OFF_E0     1019904    // [B][S]             = 400
#define OFF_ATT    1020304    // [B][S][HW]         = 313600
#define OFF_EP     1333904    // [CSPLIT][B][S][HW] = 2508800
#define OFF_KK     1333904    // alias: [B][CI][SP] = 229376
#define OFF_P      1563280    // alias: [KC][B][4sh][256t][28] = 1835008
#define OFF_BAR    3842704    // 2 x unsigned {count, gen} at region end (64B-aligned)

// Device-scope grid barrier. All NBLK blocks are co-resident (launch_bounds
// guarantees 4 blocks/CU; LDS 14336B allows 11). Self-cleaning: count returns
// to 0 at every release, gen is read dynamically -> safe under rocprof replay.
__device__ __forceinline__ void gbar(unsigned* bar) {
    __syncthreads();                       // drains this block's stores (vmcnt 0)
    if (threadIdx.x == 0) {
        unsigned g = __hip_atomic_load(bar + 1, __ATOMIC_RELAXED, __HIP_MEMORY_SCOPE_AGENT);
        unsigned a = __hip_atomic_fetch_add(bar, 1u, __ATOMIC_ACQ_REL, __HIP_MEMORY_SCOPE_AGENT);
        if (a == (unsigned)(NBLK - 1)) {
            __hip_atomic_store(bar, 0u, __ATOMIC_RELAXED, __HIP_MEMORY_SCOPE_AGENT);
            __hip_atomic_fetch_add(bar + 1, 1u, __ATOMIC_RELEASE, __HIP_MEMORY_SCOPE_AGENT);
        } else {
            int spins = 0;
            while (__hip_atomic_load(bar + 1, __ATOMIC_RELAXED, __HIP_MEMORY_SCOPE_AGENT) == g) {
                __builtin_amdgcn_s_sleep(1);
                if (++spins > (1 << 22)) break;   // safety valve: never hard-hang
            }
        }
        __threadfence();                   // agent acquire: inv L1/L2 before phase reads
    }
    __syncthreads();
}

// kk/v projection body (K=256), identical to 8-kernel version
template <int NS>
__device__ __forceinline__ void proj_body(const float* __restrict__ wrow,
                                          const float* __restrict__ pb, int s0,
                                          float bias, float* __restrict__ dst,
                                          bool zpad) {
    float acc[NS];
#pragma unroll
    for (int i = 0; i < NS; ++i) acc[i] = 0.f;
    const float4* w4 = (const float4*)wrow;
#pragma unroll 4
    for (int c4 = 0; c4 < CS / 4; ++c4) {
        float4 w = w4[c4];
        const float* p = pb + c4 * 4 * SSZ + s0;
#pragma unroll
        for (int i = 0; i < NS; ++i)
            acc[i] = fmaf(w.x, p[i],
                     fmaf(w.y, p[SSZ + i],
                     fmaf(w.z, p[2 * SSZ + i],
                     fmaf(w.w, p[3 * SSZ + i], acc[i]))));
    }
#pragma unroll
    for (int i = 0; i < NS; ++i) dst[s0 + i] = acc[i] + bias;
    if (zpad) { dst[25] = 0.f; dst[26] = 0.f; dst[27] = 0.f; }
}

__global__ __launch_bounds__(256, 4) void mega(
    const float* __restrict__ xr, const float* __restrict__ xs,
    const float* __restrict__ Wq, const float* __restrict__ bq,
    const float* __restrict__ Wk, const float* __restrict__ bk,
    const float* __restrict__ Wv, const float* __restrict__ bv,
    const float* __restrict__ gm, float* __restrict__ out,
    float* __restrict__ ws)
{
    __shared__ __align__(16) float lds[CCHUNK * SP];   // 14336 B, reused per phase

    float* pooled = ws + OFF_POOLED;
    float* vp     = ws + OFF_VP;
    float* Mp     = ws + OFF_MP;
    float* e0     = ws + OFF_E0;
    float* att    = ws + OFF_ATT;
    float* Ep     = ws + OFF_EP;
    float* kk     = ws + OFF_KK;
    float* P      = ws + OFF_P;
    unsigned* bar = (unsigned*)(ws + OFF_BAR);

    const int tid  = threadIdx.x;
    const int wave = tid >> 6, lane = tid & 63;
    const int bid  = blockIdx.x;

    // ---------------- P1: pooled = mean over width ----------------
    {
        int id = bid * 256 + tid;                      // 102400 outputs, one pass
        if (id < BB * CS * SSZ) {
            const float* row = xs + (size_t)id * SSZ;
            float s = 0.f;
#pragma unroll
            for (int w = 0; w < SSZ; ++w) s += row[w];
            pooled[id] = s * (1.0f / SSZ);
        }
    }
    gbar(bar);

    // ---------------- P2: kk = Wk*pooled + bk ; v = Wv*pooled + bv ----------------
    if (bid < 24 * BB) {                               // 384 block-tasks
        int xx = bid % 24, b = bid / 24;
        int rb = xx >> 2, sh = xx & 3;
        const float* pb = pooled + (size_t)b * CS * SSZ;
        const float* wrow; float bias; float* dst;
        if (rb < 2) {
            int i = rb * 256 + tid;
            wrow = Wk + (size_t)i * CS; bias = bk[i];
            dst  = kk + ((size_t)b * CI + i) * SP;
        } else {
            int r = (rb - 2) * 256 + tid;
            wrow = Wv + (size_t)r * CS; bias = bv[r];
            dst  = vp + ((size_t)b * CR + r) * SP;
        }
        int s0 = sh * 7;
        if (sh < 3) proj_body<7>(wrow, pb, s0, bias, dst, false);
        else        proj_body<4>(wrow, pb, s0, bias, dst, true);
    }
    gbar(bar);

    // ---------------- P3: M partials via LDS-broadcast GEMM ----------------
    if (bid < 4 * KC * BB) {                           // 256 block-tasks
        int sh = bid & 3, kc = (bid >> 2) & 3, b = bid >> 4;
        int s0 = sh * 7, i0 = kc * 128;
        const float* kkb = kk + (size_t)b * CI * SP;
#pragma unroll
        for (int q = 0; q < 4; ++q) {
            int d = tid + 256 * q;                     // row=d>>3, col=d&7 (col7 slack)
            lds[d] = kkb[(size_t)(i0 + (d >> 3)) * SP + s0 + (d & 7)];
        }
        __syncthreads();
        float acc[28];
#pragma unroll
        for (int e = 0; e < 28; ++e) acc[e] = 0.f;
        const float4* lds4 = (const float4*)lds;
#pragma unroll 4
        for (int i = 0; i < 128; ++i) {
            float4 w = *(const float4*)(Wq + (size_t)(i0 + i) * CR + 4 * tid);
            float4 k0 = lds4[i * 2];
            float4 k1 = lds4[i * 2 + 1];
#pragma unroll
            for (int j = 0; j < 4; ++j) {
                float wj = j == 0 ? w.x : j == 1 ? w.y : j == 2 ? w.z : w.w;
                acc[j * 7 + 0] = fmaf(wj, k0.x, acc[j * 7 + 0]);
                acc[j * 7 + 1] = fmaf(wj, k0.y, acc[j * 7 + 1]);
                acc[j * 7 + 2] = fmaf(wj, k0.z, acc[j * 7 + 2]);
                acc[j * 7 + 3] = fmaf(wj, k0.w, acc[j * 7 + 3]);
                acc[j * 7 + 4] = fmaf(wj, k1.x, acc[j * 7 + 4]);
                acc[j * 7 + 5] = fmaf(wj, k1.y, acc[j * 7 + 5]);
                acc[j * 7 + 6] = fmaf(wj, k1.z, acc[j * 7 + 6]);
            }
        }
        float* dstP = P + ((((size_t)kc * BB + b) * 4 + sh) * 256 + tid) * 28;
#pragma unroll
        for (int m = 0; m < 7; ++m) {
            float4 o;
            o.x = acc[4 * m + 0]; o.y = acc[4 * m + 1];
            o.z = acc[4 * m + 2]; o.w = acc[4 * m + 3];
            *(float4*)(dstP + 4 * m) = o;
        }
    }
    gbar(bar);

    // ---------------- P4: Mp = sum_kc P  (+ e0 on blocks 64..163) ----------------
    if (bid < 64) {
        int id = bid * 256 + tid;
        int t = id & 255, sh = (id >> 8) & 3, b = id >> 10;
        const float* p0 = P + ((((size_t)b) * 4 + sh) * 256 + t) * 28;
        const size_t PL = (size_t)BB * 4 * 256 * 28;
        float vv[28];
#pragma unroll
        for (int m = 0; m < 7; ++m) {
            float4 a  = *(const float4*)(p0 + 4 * m);
            float4 b1 = *(const float4*)(p0 + PL + 4 * m);
            float4 c  = *(const float4*)(p0 + 2 * PL + 4 * m);
            float4 d  = *(const float4*)(p0 + 3 * PL + 4 * m);
            vv[4 * m + 0] = a.x + b1.x + c.x + d.x;
            vv[4 * m + 1] = a.y + b1.y + c.y + d.y;
            vv[4 * m + 2] = a.z + b1.z + c.z + d.z;
            vv[4 * m + 3] = a.w + b1.w + c.w + d.w;
        }
        int s0 = sh * 7;
        float* mb = Mp + ((size_t)b * CR + 4 * t) * SP + s0;
#pragma unroll
        for (int j = 0; j < 4; ++j)
#pragma unroll
            for (int u = 0; u < 7; ++u)
                mb[j * SP + u] = vv[j * 7 + u];
    } else if (bid < 164) {
        int wtask = (bid - 64) * 4 + wave;             // 0..399 = (b,s) wave-tasks
        int s = wtask % 25, b = wtask / 25;
        const float* kb = kk + (size_t)b * CI * SP;
        float a = 0.f;
#pragma unroll
        for (int k = 0; k < CI / 64; ++k) {
            int i = lane + 64 * k;
            a = fmaf(bq[i], kb[(size_t)i * SP + s], a);
        }
#pragma unroll
        for (int off = 32; off > 0; off >>= 1) a += __shfl_down(a, off);
        if (lane == 0) e0[b * SSZ + s] = a;
    }
    gbar(bar);   // also protects Ep overwrite of kk|P aliases

    // ---------------- P5: partial energies Ep[ch][b][s][n] ----------------
    if (bid < 2 * CSPLIT * BB) {                       // 256 block-tasks
        int nq = bid & 1, ch = (bid >> 1) & 7, b = bid >> 4;
        int cbeg = ch * CCHUNK;
        {
            const float4* src = (const float4*)(Mp + ((size_t)b * CR + cbeg) * SP);
            float4* dst = (float4*)lds;
#pragma unroll
            for (int j = 0; j < 4; ++j) {
                int idx = tid + 256 * j;
                if (idx < CCHUNK * SP / 4) dst[idx] = src[idx];
            }
        }
        __syncthreads();
        int u = nq * 4 + wave;
        if (u < 7) {
            int n2 = u * 64 + lane;
            bool valid = n2 < HW2;
            int n2c = valid ? n2 : 0;
            const float2* x2 = (const float2*)(xr + (size_t)b * CR * HWD);
            float acc0[SP], acc1[SP];
#pragma unroll
            for (int s = 0; s < SP; ++s) { acc0[s] = 0.f; acc1[s] = 0.f; }
            for (int c = 0; c < CCHUNK; c += 8) {      // 8 loads in flight (1 wave/SIMD here)
                float2 xv[8];
#pragma unroll
                for (int q = 0; q < 8; ++q)
                    xv[q] = x2[(size_t)(cbeg + c + q) * HW2 + n2c];
#pragma unroll
                for (int q = 0; q < 8; ++q) {
                    const float4* mr = (const float4*)&lds[(c + q) * SP];
#pragma unroll
                    for (int j = 0; j < 7; ++j) {
                        float4 m = mr[j];
                        acc0[4 * j + 0] = fmaf(xv[q].x, m.x, acc0[4 * j + 0]);
                        acc0[4 * j + 1] = fmaf(xv[q].x, m.y, acc0[4 * j + 1]);
                        acc0[4 * j + 2] = fmaf(xv[q].x, m.z, acc0[4 * j + 2]);
                        acc0[4 * j + 3] = fmaf(xv[q].x, m.w, acc0[4 * j + 3]);
                        acc1[4 * j + 0] = fmaf(xv[q].y, m.x, acc1[4 * j + 0]);
                        acc1[4 * j + 1] = fmaf(xv[q].y, m.y, acc1[4 * j + 1]);
                        acc1[4 * j + 2] = fmaf(xv[q].y, m.z, acc1[4 * j + 2]);
                        acc1[4 * j + 3] = fmaf(xv[q].y, m.w, acc1[4 * j + 3]);
                    }
                }
            }
            if (valid) {
                float2* ep = (float2*)Ep + ((size_t)(ch * BB + b) * SSZ) * HW2 + n2;
#pragma unroll
                for (int s = 0; s < SSZ; ++s)
                    ep[(size_t)s * HW2] = make_float2(acc0[s], acc1[s]);
            }
        }
    }
    gbar(bar);

    // ---------------- P6: att = softmax_s(sum_ch Ep + e0) ----------------
    if (bid < 28) {
        int wtask = bid * 4 + wave;                    // 0..111
        int nb = wtask % 7, b = wtask / 7;
        int n2 = nb * 64 + lane;
        if (n2 < HW2) {
            float ex[SSZ], ey[SSZ];
#pragma unroll
            for (int s = 0; s < SSZ; ++s) { float v = e0[b * SSZ + s]; ex[s] = v; ey[s] = v; }
            const float2* ep2 = (const float2*)Ep;
            for (int ch = 0; ch < CSPLIT; ++ch) {
                const float2* ep = ep2 + ((size_t)(ch * BB + b) * SSZ) * HW2 + n2;
#pragma unroll
                for (int s = 0; s < SSZ; ++s) {
                    float2 v = ep[(size_t)s * HW2];
                    ex[s] += v.x; ey[s] += v.y;
                }
            }
            float mx = ex[0], my = ey[0];
#pragma unroll
            for (int s = 1; s < SSZ; ++s) { mx = fmaxf(mx, ex[s]); my = fmaxf(my, ey[s]); }
            float sx = 0.f, sy = 0.f;
#pragma unroll
            for (int s = 0; s < SSZ; ++s) {
                ex[s] = __expf(ex[s] - mx); sx += ex[s];
                ey[s] = __expf(ey[s] - my); sy += ey[s];
            }
            float ix = 1.0f / sx, iy = 1.0f / sy;
            float2* ao = (float2*)att + ((size_t)b * SSZ) * HW2 + n2;
#pragma unroll
            for (int s = 0; s < SSZ; ++s)
                ao[(size_t)s * HW2] = make_float2(ex[s] * ix, ey[s] * iy);
        }
    }
    gbar(bar);

    // ---------------- P7: out = gamma * (v·att) + x_rgb ----------------
    {
        int nq = bid & 1, rz = (bid >> 1) & 31, b = bid >> 6;   // exactly 1024 tasks
        int r0 = rz * RCHUNK;
        {
            const float4* src = (const float4*)(vp + ((size_t)b * CR + r0) * SP);
            float4* dst = (float4*)lds;
            if (tid < RCHUNK * SP / 4) dst[tid] = src[tid];
        }
        __syncthreads();
        int u = nq * 4 + wave;
        if (u < 7) {
            int n2 = u * 64 + lane;
            bool valid = n2 < HW2;
            int n2c = valid ? n2 : 0;
            float a0[SP], a1[SP];
            const float2* at2 = (const float2*)att + ((size_t)b * SSZ) * HW2 + n2c;
#pragma unroll
            for (int s = 0; s < SSZ; ++s) {
                float2 av = at2[(size_t)s * HW2];
                a0[s] = av.x; a1[s] = av.y;
            }
#pragma unroll
            for (int s = SSZ; s < SP; ++s) { a0[s] = 0.f; a1[s] = 0.f; }
            float g = gm[0];
            const float2* x2 = (const float2*)(xr + (size_t)b * CR * HWD);
            float2* o2 = (float2*)(out + (size_t)b * CR * HWD);
#pragma unroll 4
            for (int r = 0; r < RCHUNK; ++r) {
                float2 xv = x2[(size_t)(r0 + r) * HW2 + n2c];
                float d0 = 0.f, d1 = 0.f;
                const float4* vr = (const float4*)&lds[r * SP];
#pragma unroll
                for (int j = 0; j < 7; ++j) {
                    float4 v = vr[j];
                    d0 = fmaf(v.x, a0[4 * j + 0], d0);
                    d0 = fmaf(v.y, a0[4 * j + 1], d0);
                    d0 = fmaf(v.z, a0[4 * j + 2], d0);
                    d0 = fmaf(v.w, a0[4 * j + 3], d0);
                    d1 = fmaf(v.x, a1[4 * j + 0], d1);
                    d1 = fmaf(v.y, a1[4 * j + 1], d1);
                    d1 = fmaf(v.z, a1[4 * j + 2], d1);
                    d1 = fmaf(v.w, a1[4 * j + 3], d1);
                }
                if (valid)
                    o2[(size_t)(r0 + r) * HW2 + n2] =
                        make_float2(fmaf(g, d0, xv.x), fmaf(g, d1, xv.y));
            }
        }
    }
}

extern "C" void kernel_launch(void* const* d_in, const int* in_sizes, int n_in,
                              void* d_out, int out_size, void* d_ws, size_t ws_size,
                              hipStream_t stream) {
    const float* x_rgb  = (const float*)d_in[0];
    const float* x_skel = (const float*)d_in[1];
    const float* Wq     = (const float*)d_in[2];
    const float* bq     = (const float*)d_in[3];
    const float* Wk     = (const float*)d_in[4];
    const float* bk     = (const float*)d_in[5];
    const float* Wv     = (const float*)d_in[6];
    const float* bv     = (const float*)d_in[7];
    const float* gamma  = (const float*)d_in[8];
    float* out = (float*)d_out;
    float* ws  = (float*)d_ws;

    // Zero the grid-barrier {count, gen} every replay (stream-ordered, capturable).
    hipMemsetAsync(ws + OFF_BAR, 0, 2 * sizeof(unsigned), stream);

    hipLaunchKernelGGL(mega, dim3(NBLK), dim3(256), 0, stream,
                       x_rgb, x_skel, Wq, bq, Wk, bk, Wv, bv, gamma, out, ws);
}

// Round 2
// 607.588 us; speedup vs baseline: 1.2219x; 1.2219x over previous
//
#include <hip/hip_runtime.h>

// Problem dims (fixed by setup_inputs)
#define BB 16
#define CR 1024
#define HWD 784     // 28*28
#define HW2 392     // HWD/2 (float2 units)
#define CS 256
#define SSZ 25
#define SP 28       // padded row length for kk/M/v
#define CI 512
#define CSPLIT 8    // c-chunks in energy (each 128)
#define CCHUNK 128
#define RCHUNK 32
#define KC 4
#define NBLK 1024   // 4 blocks/CU x 256 CUs -- all co-resident by __launch_bounds__(256,4)

// Workspace layout (floats). Same as 8-kernel version; Ep aliases kk|P (dead by P5).
#define OFF_POOLED 0          // [B][CS][S]         = 102400
#define OFF_VP     102400     // [B][CR][SP]        = 458752
#define OFF_MP     561152     // [B][CR][SP]        = 458752
#define OFF_E0     1019904    // [B][S]             = 400
#define OFF_ATT    1020304    // [B][S][HW]         = 313600
#define OFF_EP     1333904    // [CSPLIT][B][S][HW] = 2508800
#define OFF_KK     1333904    // alias: [B][CI][SP] = 229376
#define OFF_P      1563280    // alias: [KC][B][4sh][256t][28] = 1835008
#define OFF_BAR    3842704    // hierarchical barrier slots (4160 B), 64B-aligned

// ---- Hierarchical grid barrier ------------------------------------------------
// Round-1 flat barrier cost ~100us/barrier: 1024 same-line agent-scope RMWs
// serialize, and 1023 same-line polls slow the chain further. Fix: 2-level tree.
//   level0: 32 groups x 32 blocks, each group's counter on its OWN 64B slot
//           -> 32 parallel chains of only 32 serialized RMWs
//   level1: 32 group leaders on one top slot (32 serialized RMWs)
//   release: last leader bumps 32 per-group generation slots (release order);
//            spinners poll ONLY their group's gen slot (<=32 pollers/line).
// Self-cleaning (counters return to 0, gens monotone) -> rocprof-replay safe.
#define NGRP  32
#define GRPSZ 32
#define SLOT  16    // uints per slot = 64B
// uint layout at barBase: grpCnt[g]=g*SLOT ; topCnt=NGRP*SLOT ; gen[g]=(NGRP+1+g)*SLOT
#define BAR_UINTS ((2 * NGRP + 1) * SLOT)   // 1040 uints = 4160 B

__device__ __forceinline__ void gbar(unsigned* bar) {
    __syncthreads();                       // block's stores drained (vmcnt 0)
    if (threadIdx.x == 0) {
        const int g = blockIdx.x >> 5;     // 32 blocks per group
        unsigned* grp = bar + g * SLOT;
        unsigned* top = bar + NGRP * SLOT;
        unsigned* gen = bar + (NGRP + 1 + g) * SLOT;
        unsigned g0 = __hip_atomic_load(gen, __ATOMIC_RELAXED, __HIP_MEMORY_SCOPE_AGENT);
        unsigned a = __hip_atomic_fetch_add(grp, 1u, __ATOMIC_ACQ_REL, __HIP_MEMORY_SCOPE_AGENT);
        if (a == GRPSZ - 1) {
            __hip_atomic_store(grp, 0u, __ATOMIC_RELAXED, __HIP_MEMORY_SCOPE_AGENT);
            unsigned t = __hip_atomic_fetch_add(top, 1u, __ATOMIC_ACQ_REL, __HIP_MEMORY_SCOPE_AGENT);
            if (t == NGRP - 1) {
                __hip_atomic_store(top, 0u, __ATOMIC_RELAXED, __HIP_MEMORY_SCOPE_AGENT);
#pragma unroll
                for (int i = 0; i < NGRP; ++i)
                    __hip_atomic_fetch_add(bar + (NGRP + 1 + i) * SLOT, 1u,
                                           __ATOMIC_RELEASE, __HIP_MEMORY_SCOPE_AGENT);
                // own gen already bumped -> spin below exits immediately
            }
        }
        {
            int spins = 0;
            while (__hip_atomic_load(gen, __ATOMIC_RELAXED, __HIP_MEMORY_SCOPE_AGENT) == g0) {
                __builtin_amdgcn_s_sleep(2);
                if (++spins > (1 << 22)) break;   // safety valve: never hard-hang
            }
        }
        __threadfence();                   // agent acquire before phase-N+1 reads
    }
    __syncthreads();
}

// kk/v projection body (K=256), identical to 8-kernel version
template <int NS>
__device__ __forceinline__ void proj_body(const float* __restrict__ wrow,
                                          const float* __restrict__ pb, int s0,
                                          float bias, float* __restrict__ dst,
                                          bool zpad) {
    float acc[NS];
#pragma unroll
    for (int i = 0; i < NS; ++i) acc[i] = 0.f;
    const float4* w4 = (const float4*)wrow;
#pragma unroll 4
    for (int c4 = 0; c4 < CS / 4; ++c4) {
        float4 w = w4[c4];
        const float* p = pb + c4 * 4 * SSZ + s0;
#pragma unroll
        for (int i = 0; i < NS; ++i)
            acc[i] = fmaf(w.x, p[i],
                     fmaf(w.y, p[SSZ + i],
                     fmaf(w.z, p[2 * SSZ + i],
                     fmaf(w.w, p[3 * SSZ + i], acc[i]))));
    }
#pragma unroll
    for (int i = 0; i < NS; ++i) dst[s0 + i] = acc[i] + bias;
    if (zpad) { dst[25] = 0.f; dst[26] = 0.f; dst[27] = 0.f; }
}

__global__ __launch_bounds__(256, 4) void mega(
    const float* __restrict__ xr, const float* __restrict__ xs,
    const float* __restrict__ Wq, const float* __restrict__ bq,
    const float* __restrict__ Wk, const float* __restrict__ bk,
    const float* __restrict__ Wv, const float* __restrict__ bv,
    const float* __restrict__ gm, float* __restrict__ out,
    float* __restrict__ ws)
{
    __shared__ __align__(16) float lds[CCHUNK * SP];   // 14336 B, reused per phase

    float* pooled = ws + OFF_POOLED;
    float* vp     = ws + OFF_VP;
    float* Mp     = ws + OFF_MP;
    float* e0     = ws + OFF_E0;
    float* att    = ws + OFF_ATT;
    float* Ep     = ws + OFF_EP;
    float* kk     = ws + OFF_KK;
    float* P      = ws + OFF_P;
    unsigned* bar = (unsigned*)(ws + OFF_BAR);

    const int tid  = threadIdx.x;
    const int wave = tid >> 6, lane = tid & 63;
    const int bid  = blockIdx.x;

    // ---------------- P1: pooled = mean over width ----------------
    {
        int id = bid * 256 + tid;                      // 102400 outputs, one pass
        if (id < BB * CS * SSZ) {
            const float* row = xs + (size_t)id * SSZ;
            float s = 0.f;
#pragma unroll
            for (int w = 0; w < SSZ; ++w) s += row[w];
            pooled[id] = s * (1.0f / SSZ);
        }
    }
    gbar(bar);

    // ---------------- P2: kk = Wk*pooled + bk ; v = Wv*pooled + bv ----------------
    if (bid < 24 * BB) {                               // 384 block-tasks
        int xx = bid % 24, b = bid / 24;
        int rb = xx >> 2, sh = xx & 3;
        const float* pb = pooled + (size_t)b * CS * SSZ;
        const float* wrow; float bias; float* dst;
        if (rb < 2) {
            int i = rb * 256 + tid;
            wrow = Wk + (size_t)i * CS; bias = bk[i];
            dst  = kk + ((size_t)b * CI + i) * SP;
        } else {
            int r = (rb - 2) * 256 + tid;
            wrow = Wv + (size_t)r * CS; bias = bv[r];
            dst  = vp + ((size_t)b * CR + r) * SP;
        }
        int s0 = sh * 7;
        if (sh < 3) proj_body<7>(wrow, pb, s0, bias, dst, false);
        else        proj_body<4>(wrow, pb, s0, bias, dst, true);
    }
    gbar(bar);

    // ---------------- P3: M partials via LDS-broadcast GEMM ----------------
    if (bid < 4 * KC * BB) {                           // 256 block-tasks
        int sh = bid & 3, kc = (bid >> 2) & 3, b = bid >> 4;
        int s0 = sh * 7, i0 = kc * 128;
        const float* kkb = kk + (size_t)b * CI * SP;
#pragma unroll
        for (int q = 0; q < 4; ++q) {
            int d = tid + 256 * q;                     // row=d>>3, col=d&7 (col7 slack)
            lds[d] = kkb[(size_t)(i0 + (d >> 3)) * SP + s0 + (d & 7)];
        }
        __syncthreads();
        float acc[28];
#pragma unroll
        for (int e = 0; e < 28; ++e) acc[e] = 0.f;
        const float4* lds4 = (const float4*)lds;
#pragma unroll 4
        for (int i = 0; i < 128; ++i) {
            float4 w = *(const float4*)(Wq + (size_t)(i0 + i) * CR + 4 * tid);
            float4 k0 = lds4[i * 2];
            float4 k1 = lds4[i * 2 + 1];
#pragma unroll
            for (int j = 0; j < 4; ++j) {
                float wj = j == 0 ? w.x : j == 1 ? w.y : j == 2 ? w.z : w.w;
                acc[j * 7 + 0] = fmaf(wj, k0.x, acc[j * 7 + 0]);
                acc[j * 7 + 1] = fmaf(wj, k0.y, acc[j * 7 + 1]);
                acc[j * 7 + 2] = fmaf(wj, k0.z, acc[j * 7 + 2]);
                acc[j * 7 + 3] = fmaf(wj, k0.w, acc[j * 7 + 3]);
                acc[j * 7 + 4] = fmaf(wj, k1.x, acc[j * 7 + 4]);
                acc[j * 7 + 5] = fmaf(wj, k1.y, acc[j * 7 + 5]);
                acc[j * 7 + 6] = fmaf(wj, k1.z, acc[j * 7 + 6]);
            }
        }
        float* dstP = P + ((((size_t)kc * BB + b) * 4 + sh) * 256 + tid) * 28;
#pragma unroll
        for (int m = 0; m < 7; ++m) {
            float4 o;
            o.x = acc[4 * m + 0]; o.y = acc[4 * m + 1];
            o.z = acc[4 * m + 2]; o.w = acc[4 * m + 3];
            *(float4*)(dstP + 4 * m) = o;
        }
    }
    gbar(bar);

    // ---------------- P4: Mp = sum_kc P  (+ e0 on blocks 64..163) ----------------
    if (bid < 64) {
        int id = bid * 256 + tid;
        int t = id & 255, sh = (id >> 8) & 3, b = id >> 10;
        const float* p0 = P + ((((size_t)b) * 4 + sh) * 256 + t) * 28;
        const size_t PL = (size_t)BB * 4 * 256 * 28;
        float vv[28];
#pragma unroll
        for (int m = 0; m < 7; ++m) {
            float4 a  = *(const float4*)(p0 + 4 * m);
            float4 b1 = *(const float4*)(p0 + PL + 4 * m);
            float4 c  = *(const float4*)(p0 + 2 * PL + 4 * m);
            float4 d  = *(const float4*)(p0 + 3 * PL + 4 * m);
            vv[4 * m + 0] = a.x + b1.x + c.x + d.x;
            vv[4 * m + 1] = a.y + b1.y + c.y + d.y;
            vv[4 * m + 2] = a.z + b1.z + c.z + d.z;
            vv[4 * m + 3] = a.w + b1.w + c.w + d.w;
        }
        int s0 = sh * 7;
        float* mb = Mp + ((size_t)b * CR + 4 * t) * SP + s0;
#pragma unroll
        for (int j = 0; j < 4; ++j)
#pragma unroll
            for (int u = 0; u < 7; ++u)
                mb[j * SP + u] = vv[j * 7 + u];
    } else if (bid < 164) {
        int wtask = (bid - 64) * 4 + wave;             // 0..399 = (b,s) wave-tasks
        int s = wtask % 25, b = wtask / 25;
        const float* kb = kk + (size_t)b * CI * SP;
        float a = 0.f;
#pragma unroll
        for (int k = 0; k < CI / 64; ++k) {
            int i = lane + 64 * k;
            a = fmaf(bq[i], kb[(size_t)i * SP + s], a);
        }
#pragma unroll
        for (int off = 32; off > 0; off >>= 1) a += __shfl_down(a, off);
        if (lane == 0) e0[b * SSZ + s] = a;
    }
    gbar(bar);   // also protects Ep overwrite of kk|P aliases

    // ---------------- P5: partial energies Ep[ch][b][s][n] ----------------
    if (bid < 2 * CSPLIT * BB) {                       // 256 block-tasks
        int nq = bid & 1, ch = (bid >> 1) & 7, b = bid >> 4;
        int cbeg = ch * CCHUNK;
        {
            const float4* src = (const float4*)(Mp + ((size_t)b * CR + cbeg) * SP);
            float4* dst = (float4*)lds;
#pragma unroll
            for (int j = 0; j < 4; ++j) {
                int idx = tid + 256 * j;
                if (idx < CCHUNK * SP / 4) dst[idx] = src[idx];
            }
        }
        __syncthreads();
        int u = nq * 4 + wave;
        if (u < 7) {
            int n2 = u * 64 + lane;
            bool valid = n2 < HW2;
            int n2c = valid ? n2 : 0;
            const float2* x2 = (const float2*)(xr + (size_t)b * CR * HWD);
            float acc0[SP], acc1[SP];
#pragma unroll
            for (int s = 0; s < SP; ++s) { acc0[s] = 0.f; acc1[s] = 0.f; }
            for (int c = 0; c < CCHUNK; c += 8) {      // 8 loads in flight
                float2 xv[8];
#pragma unroll
                for (int q = 0; q < 8; ++q)
                    xv[q] = x2[(size_t)(cbeg + c + q) * HW2 + n2c];
#pragma unroll
                for (int q = 0; q < 8; ++q) {
                    const float4* mr = (const float4*)&lds[(c + q) * SP];
#pragma unroll
                    for (int j = 0; j < 7; ++j) {
                        float4 m = mr[j];
                        acc0[4 * j + 0] = fmaf(xv[q].x, m.x, acc0[4 * j + 0]);
                        acc0[4 * j + 1] = fmaf(xv[q].x, m.y, acc0[4 * j + 1]);
                        acc0[4 * j + 2] = fmaf(xv[q].x, m.z, acc0[4 * j + 2]);
                        acc0[4 * j + 3] = fmaf(xv[q].x, m.w, acc0[4 * j + 3]);
                        acc1[4 * j + 0] = fmaf(xv[q].y, m.x, acc1[4 * j + 0]);
                        acc1[4 * j + 1] = fmaf(xv[q].y, m.y, acc1[4 * j + 1]);
                        acc1[4 * j + 2] = fmaf(xv[q].y, m.z, acc1[4 * j + 2]);
                        acc1[4 * j + 3] = fmaf(xv[q].y, m.w, acc1[4 * j + 3]);
                    }
                }
            }
            if (valid) {
                float2* ep = (float2*)Ep + ((size_t)(ch * BB + b) * SSZ) * HW2 + n2;
#pragma unroll
                for (int s = 0; s < SSZ; ++s)
                    ep[(size_t)s * HW2] = make_float2(acc0[s], acc1[s]);
            }
        }
    }
    gbar(bar);

    // ---------------- P6: att = softmax_s(sum_ch Ep + e0) ----------------
    // 112 blocks (was 28); 4 waves split the s-dim 7/7/7/4 (unrolled+predicated
    // so arrays stay in registers); cross-wave max/sum via 4KB LDS exchange.
    if (bid < 7 * BB) {
        int nqb = bid % 7, b = bid / 7;
        int n2 = nqb * 64 + lane;
        bool valid = n2 < HW2;
        int n2c = valid ? n2 : 0;
        const int sbeg = wave * 7;                     // wave3: only si<4 valid
        float ex[7], ey[7];
#pragma unroll
        for (int si = 0; si < 7; ++si) {
            int sc = sbeg + si; if (sc > SSZ - 1) sc = SSZ - 1;
            float v = e0[b * SSZ + sc]; ex[si] = v; ey[si] = v;
        }
        const float2* ep2 = (const float2*)Ep;
        for (int ch = 0; ch < CSPLIT; ++ch) {
            const float2* epb = ep2 + ((size_t)(ch * BB + b) * SSZ) * HW2 + n2c;
#pragma unroll
            for (int si = 0; si < 7; ++si) {
                int sc = sbeg + si; if (sc > SSZ - 1) sc = SSZ - 1;
                float2 v = epb[(size_t)sc * HW2];
                ex[si] += v.x; ey[si] += v.y;          // si>=valid range is garbage, masked later
            }
        }
        float mx = ex[0], my = ey[0];
#pragma unroll
        for (int si = 1; si < 7; ++si)
            if (sbeg + si < SSZ) { mx = fmaxf(mx, ex[si]); my = fmaxf(my, ey[si]); }
        float2* red = (float2*)lds;                    // [0..255] max, [256..511] sum
        red[wave * 64 + lane] = make_float2(mx, my);
        __syncthreads();
        float2 m0 = red[lane], m1 = red[64 + lane], m2 = red[128 + lane], m3 = red[192 + lane];
        float gmx = fmaxf(fmaxf(m0.x, m1.x), fmaxf(m2.x, m3.x));
        float gmy = fmaxf(fmaxf(m0.y, m1.y), fmaxf(m2.y, m3.y));
        float sx = 0.f, sy = 0.f;
#pragma unroll
        for (int si = 0; si < 7; ++si) {
            if (sbeg + si < SSZ) {
                ex[si] = __expf(ex[si] - gmx); sx += ex[si];
                ey[si] = __expf(ey[si] - gmy); sy += ey[si];
            }
        }
        red[256 + wave * 64 + lane] = make_float2(sx, sy);
        __syncthreads();
        float2 s0v = red[256 + lane], s1v = red[256 + 64 + lane];
        float2 s2v = red[256 + 128 + lane], s3v = red[256 + 192 + lane];
        float ix = 1.0f / (s0v.x + s1v.x + s2v.x + s3v.x);
        float iy = 1.0f / (s0v.y + s1v.y + s2v.y + s3v.y);
        if (valid) {
            float2* ao = (float2*)att + ((size_t)b * SSZ + sbeg) * HW2 + n2;
#pragma unroll
            for (int si = 0; si < 7; ++si)
                if (sbeg + si < SSZ)
                    ao[(size_t)si * HW2] = make_float2(ex[si] * ix, ey[si] * iy);
        }
    }
    gbar(bar);

    // ---------------- P7: out = gamma * (v·att) + x_rgb ----------------
    {
        int nq = bid & 1, rz = (bid >> 1) & 31, b = bid >> 6;   // exactly 1024 tasks
        int r0 = rz * RCHUNK;
        {
            const float4* src = (const float4*)(vp + ((size_t)b * CR + r0) * SP);
            float4* dst = (float4*)lds;
            if (tid < RCHUNK * SP / 4) dst[tid] = src[tid];
        }
        __syncthreads();
        int u = nq * 4 + wave;
        if (u < 7) {
            int n2 = u * 64 + lane;
            bool valid = n2 < HW2;
            int n2c = valid ? n2 : 0;
            float a0[SP], a1[SP];
            const float2* at2 = (const float2*)att + ((size_t)b * SSZ) * HW2 + n2c;
#pragma unroll
            for (int s = 0; s < SSZ; ++s) {
                float2 av = at2[(size_t)s * HW2];
                a0[s] = av.x; a1[s] = av.y;
            }
#pragma unroll
            for (int s = SSZ; s < SP; ++s) { a0[s] = 0.f; a1[s] = 0.f; }
            float g = gm[0];
            const float2* x2 = (const float2*)(xr + (size_t)b * CR * HWD);
            float2* o2 = (float2*)(out + (size_t)b * CR * HWD);
#pragma unroll 4
            for (int r = 0; r < RCHUNK; ++r) {
                float2 xv = x2[(size_t)(r0 + r) * HW2 + n2c];
                float d0 = 0.f, d1 = 0.f;
                const float4* vr = (const float4*)&lds[r * SP];
#pragma unroll
                for (int j = 0; j < 7; ++j) {
                    float4 v = vr[j];
                    d0 = fmaf(v.x, a0[4 * j + 0], d0);
                    d0 = fmaf(v.y, a0[4 * j + 1], d0);
                    d0 = fmaf(v.z, a0[4 * j + 2], d0);
                    d0 = fmaf(v.w, a0[4 * j + 3], d0);
                    d1 = fmaf(v.x, a1[4 * j + 0], d1);
                    d1 = fmaf(v.y, a1[4 * j + 1], d1);
                    d1 = fmaf(v.z, a1[4 * j + 2], d1);
                    d1 = fmaf(v.w, a1[4 * j + 3], d1);
                }
                if (valid)
                    o2[(size_t)(r0 + r) * HW2 + n2] =
                        make_float2(fmaf(g, d0, xv.x), fmaf(g, d1, xv.y));
            }
        }
    }
}

extern "C" void kernel_launch(void* const* d_in, const int* in_sizes, int n_in,
                              void* d_out, int out_size, void* d_ws, size_t ws_size,
                              hipStream_t stream) {
    const float* x_rgb  = (const float*)d_in[0];
    const float* x_skel = (const float*)d_in[1];
    const float* Wq     = (const float*)d_in[2];
    const float* bq     = (const float*)d_in[3];
    const float* Wk     = (const float*)d_in[4];
    const float* bk     = (const float*)d_in[5];
    const float* Wv     = (const float*)d_in[6];
    const float* bv     = (const float*)d_in[7];
    const float* gamma  = (const float*)d_in[8];
    float* out = (float*)d_out;
    float* ws  = (float*)d_ws;

    // Zero all barrier slots every replay (stream-ordered, capturable).
    hipMemsetAsync(ws + OFF_BAR, 0, BAR_UINTS * sizeof(unsigned), stream);

    hipLaunchKernelGGL(mega, dim3(NBLK), dim3(256), 0, stream,
                       x_rgb, x_skel, Wq, bq, Wk, bk, Wv, bv, gamma, out, ws);
}

// Round 4
// 301.923 us; speedup vs baseline: 2.4589x; 2.0124x over previous
//
#include <hip/hip_runtime.h>

// Problem dims (fixed by setup_inputs)
#define BB 16
#define CR 1024
#define HWD 784     // 28*28
#define HW2 392     // HWD/2 (float2 units)
#define CS 256
#define SSZ 25
#define SP 28       // padded row length for kk/M/v
#define CI 512
#define NBLK 256    // 1 block/CU; launch_bounds(256,2) -> capacity 2/CU, deadlock-free

// Workspace layout (floats) — subset of the proven footprint.
#define OFF_POOLED 0          // [B][CS][S]  = 102400
#define OFF_VP     102400     // [B][CR][SP] = 458752
#define OFF_MP     561152     // [B][CR][SP] = 458752
#define OFF_E0     1019904    // [B][S]      = 400
#define OFF_KK     1333904    // [B][CI][SP] = 229376
#define OFF_BAR    3842704    // barrier slots (768 uints)

// ---- Grid barrier: relaxed-RMW tree + ONE release/acquire fence per block ----
// Round-2 lesson: agent acq_rel per block costs ~4 L2-flash ops (wbl2/inv) x
// 1024 blocks x ~18ns serialized = ~75us/barrier. Round-3 lesson: dropping
// fences entirely is INCORRECT (relaxed atomic ld/st are not cross-XCD
// coherent; only RMWs are). So: minimal-correct = 1 wbl2 + 1 inv per block
// (256 blocks) + relaxed RMW flags. Monotone counters -> rocprof-replay safe.
#define NGRP  16
#define GRPSZ 16
#define BAR_UINTS 768   // grp[g]@g*16 (0..255), top@256, gen[g]@512+g*16

__device__ __forceinline__ void gbar(unsigned* bar, unsigned phase) {
    __syncthreads();                       // all waves' stores vmcnt-drained (in L2)
    if (threadIdx.x < 64) {
        const unsigned g = (unsigned)blockIdx.x >> 4;
        const int lane = threadIdx.x;
        unsigned tk = 0;
        if (lane == 0) {
            // flush this XCD's dirty L2 lines to L3 BEFORE signaling arrival
            __builtin_amdgcn_fence(__ATOMIC_RELEASE, "agent");
            unsigned a = __hip_atomic_fetch_add(bar + g * 16, 1u,
                           __ATOMIC_RELAXED, __HIP_MEMORY_SCOPE_AGENT);
            if (a == phase * GRPSZ - 1)    // group complete (monotone count)
                tk = 1u + __hip_atomic_fetch_add(bar + 256, 1u,
                             __ATOMIC_RELAXED, __HIP_MEMORY_SCOPE_AGENT);
        }
        tk = __shfl(tk, 0);
        if (tk == phase * NGRP && lane < NGRP)      // last group: release all
            __hip_atomic_fetch_add(bar + 512 + lane * 16, 1u,
                                   __ATOMIC_RELAXED, __HIP_MEMORY_SCOPE_AGENT);
        if (lane == 0) {
            const unsigned* gen = bar + 512 + g * 16;
            int spins = 0;
            while (__hip_atomic_load(gen, __ATOMIC_RELAXED,
                                     __HIP_MEMORY_SCOPE_AGENT) != phase) {
                __builtin_amdgcn_s_sleep(4);
                if (++spins > (1 << 22)) break;     // safety valve
            }
            // invalidate this CU's L1 + this XCD's L2 before reading fresh data
            __builtin_amdgcn_fence(__ATOMIC_ACQUIRE, "agent");
        }
    }
    __syncthreads();
}

// kk/v projection body (K=256); pooled[b] staged in LDS
template <int NS>
__device__ __forceinline__ void proj_body(const float* __restrict__ wrow,
                                          const float* __restrict__ pb, int s0,
                                          float bias, float* __restrict__ dst,
                                          bool zpad) {
    float acc[NS];
#pragma unroll
    for (int i = 0; i < NS; ++i) acc[i] = 0.f;
    const float4* w4 = (const float4*)wrow;
#pragma unroll 4
    for (int c4 = 0; c4 < CS / 4; ++c4) {
        float4 w = w4[c4];
        const float* p = pb + c4 * 4 * SSZ + s0;
#pragma unroll
        for (int i = 0; i < NS; ++i)
            acc[i] = fmaf(w.x, p[i],
                     fmaf(w.y, p[SSZ + i],
                     fmaf(w.z, p[2 * SSZ + i],
                     fmaf(w.w, p[3 * SSZ + i], acc[i]))));
    }
#pragma unroll
    for (int i = 0; i < NS; ++i) dst[s0 + i] = acc[i] + bias;
    if (zpad) { dst[25] = 0.f; dst[26] = 0.f; dst[27] = 0.f; }
}

__global__ __launch_bounds__(256, 2) void mega(
    const float* __restrict__ xr, const float* __restrict__ xs,
    const float* __restrict__ Wq, const float* __restrict__ bq,
    const float* __restrict__ Wk, const float* __restrict__ bk,
    const float* __restrict__ Wv, const float* __restrict__ bv,
    const float* __restrict__ gm, float* __restrict__ out,
    float* __restrict__ ws)
{
    // 57.6 KB static LDS (max over phases): PF part[6400 f2] + att2[800 f2]
    __shared__ __align__(16) float lds[14400];

    float* pooled = ws + OFF_POOLED;
    float* vp     = ws + OFF_VP;
    float* Mp     = ws + OFF_MP;
    float* e0     = ws + OFF_E0;
    float* kk     = ws + OFF_KK;
    unsigned* bar = (unsigned*)(ws + OFF_BAR);

    const int tid  = threadIdx.x;
    const int wave = tid >> 6, lane = tid & 63;
    const int bid  = blockIdx.x;

    // ---------------- P1: pooled = mean over width (102400 rows of 25) ----------
    {
#pragma unroll
        for (int base = 0; base < BB * CS * SSZ; base += NBLK * 256) {
            int id = base + bid * 256 + tid;
            if (id < BB * CS * SSZ) {
                const float* row = xs + (size_t)id * SSZ;
                float s = 0.f;
#pragma unroll
                for (int w = 0; w < SSZ; ++w) s += row[w];
                pooled[id] = s * (1.0f / SSZ);
            }
        }
    }
    gbar(bar, 1);

    // ---------------- P2: kk = Wk*pooled + bk ; vp = Wv*pooled + bv -------------
    for (int task = bid; task < 24 * BB; task += NBLK) {
        int xx = task % 24, b = task / 24;
        int rb = xx >> 2, sh = xx & 3;
        __syncthreads();                   // prior readers of lds done
        const float* pb = pooled + (size_t)b * CS * SSZ;
#pragma unroll
        for (int q = 0; q < 25; ++q) lds[tid + 256 * q] = pb[tid + 256 * q];
        __syncthreads();
        const float* wrow; float bias; float* dst;
        if (rb < 2) {
            int i = rb * 256 + tid;
            wrow = Wk + (size_t)i * CS; bias = bk[i];
            dst  = kk + ((size_t)b * CI + i) * SP;
        } else {
            int r = (rb - 2) * 256 + tid;
            wrow = Wv + (size_t)r * CS; bias = bv[r];
            dst  = vp + ((size_t)b * CR + r) * SP;
        }
        int s0 = sh * 7;
        if (sh < 3) proj_body<7>(wrow, lds, s0, bias, dst, false);
        else        proj_body<4>(wrow, lds, s0, bias, dst, true);
    }
    gbar(bar, 2);

    // ---------------- P3': Mp[b][c][s] = sum_i Wq[i,c]*kk[b,i,s], K=512 direct --
    // 224 blocks: (7 s-chunks of 4) x 16 b x 2 c-halves. In-block K-split by 2
    // + LDS reduce. Blocks 224..255: e0[b,s] = sum_i bq[i]*kk[b,i,s] (400 tasks).
    if (bid < 224) {
        int sc = bid % 7, rem = bid / 7;
        int b = rem >> 1, chalf = rem & 1;
        int s0 = sc * 4;
        float* kst = lds;                  // [512][4] = 2048 floats
        float* red = lds + 2048;           // [128][17] padded = 2176 floats
        const float* kkb = kk + (size_t)b * CI * SP;
#pragma unroll
        for (int q = 0; q < 8; ++q) {
            int d = tid + 256 * q;         // i = d>>2, col = d&3
            kst[d] = kkb[(size_t)(d >> 2) * SP + s0 + (d & 3)];
        }
        __syncthreads();
        int half = tid >> 7, tq = tid & 127;
        int cq = chalf * 512 + 4 * tq;     // 4 consecutive c columns
        float acc[16];
#pragma unroll
        for (int e = 0; e < 16; ++e) acc[e] = 0.f;
        const float4* kst4 = (const float4*)kst;
        int i0 = half * 256;
#pragma unroll 4
        for (int i = 0; i < 256; ++i) {
            float4 w = *(const float4*)(Wq + (size_t)(i0 + i) * CR + cq);
            float4 k = kst4[i0 + i];
#pragma unroll
            for (int cl = 0; cl < 4; ++cl) {
                float wc = cl == 0 ? w.x : cl == 1 ? w.y : cl == 2 ? w.z : w.w;
                acc[cl * 4 + 0] = fmaf(wc, k.x, acc[cl * 4 + 0]);
                acc[cl * 4 + 1] = fmaf(wc, k.y, acc[cl * 4 + 1]);
                acc[cl * 4 + 2] = fmaf(wc, k.z, acc[cl * 4 + 2]);
                acc[cl * 4 + 3] = fmaf(wc, k.w, acc[cl * 4 + 3]);
            }
        }
        if (half == 1) {
#pragma unroll
            for (int j = 0; j < 16; ++j) red[tq * 17 + j] = acc[j];
        }
        __syncthreads();
        if (half == 0) {
#pragma unroll
            for (int j = 0; j < 16; ++j) acc[j] += red[tq * 17 + j];
#pragma unroll
            for (int cl = 0; cl < 4; ++cl) {
                float4 o;
                o.x = acc[cl * 4 + 0]; o.y = acc[cl * 4 + 1];
                o.z = acc[cl * 4 + 2]; o.w = acc[cl * 4 + 3];
                *(float4*)&Mp[((size_t)(b << 10) + cq + cl) * SP + s0] = o;
            }
        }
    } else {
        int wt0 = (bid - 224) * 4 + wave;  // 128 wave-slots for 400 (b,s) tasks
        for (int wt = wt0; wt < 400; wt += 128) {
            int s = wt % 25, b = wt / 25;
            const float* kb = kk + (size_t)b * CI * SP;
            float a = 0.f;
#pragma unroll
            for (int k = 0; k < CI / 64; ++k) {
                int i = lane + 64 * k;
                a = fmaf(bq[i], kb[(size_t)i * SP + s], a);
            }
#pragma unroll
            for (int off = 32; off > 0; off >>= 1) a += __shfl_down(a, off);
            if (lane == 0) e0[b * SSZ + s] = a;
        }
    }
    gbar(bar, 3);

    // ---------------- PF: energy + softmax + out, fused per (b, n-tile) --------
    // 208 blocks = 16 b x 13 tiles of 32 float2-lanes. Threads: cg=tid>>5 (8
    // c/r-groups of 128), nl=tid&31. Energy partials in regs -> LDS reduce ->
    // softmax by 32 lanes -> out pass (r-split by cg), att from LDS.
    if (bid < 13 * BB) {
        int tile = bid % 13, b = bid / 13;
        int cg = tid >> 5, nl = tid & 31;
        int n2 = tile * 32 + nl;
        bool valid = n2 < HW2;
        int n2c = valid ? n2 : 0;
        const float2* x2 = (const float2*)(xr + (size_t)b * CR * HWD);

        float a0[SSZ], a1[SSZ];
#pragma unroll
        for (int s = 0; s < SSZ; ++s) { a0[s] = 0.f; a1[s] = 0.f; }
        const int c0 = cg * 128;
        for (int c = c0; c < c0 + 128; ++c) {
            float2 xv = x2[(size_t)c * HW2 + n2c];
            const float4* mr = (const float4*)&Mp[((size_t)(b << 10) + c) * SP];
#pragma unroll
            for (int j = 0; j < 6; ++j) {
                float4 m = mr[j];
                a0[4 * j + 0] = fmaf(xv.x, m.x, a0[4 * j + 0]);
                a0[4 * j + 1] = fmaf(xv.x, m.y, a0[4 * j + 1]);
                a0[4 * j + 2] = fmaf(xv.x, m.z, a0[4 * j + 2]);
                a0[4 * j + 3] = fmaf(xv.x, m.w, a0[4 * j + 3]);
                a1[4 * j + 0] = fmaf(xv.y, m.x, a1[4 * j + 0]);
                a1[4 * j + 1] = fmaf(xv.y, m.y, a1[4 * j + 1]);
                a1[4 * j + 2] = fmaf(xv.y, m.z, a1[4 * j + 2]);
                a1[4 * j + 3] = fmaf(xv.y, m.w, a1[4 * j + 3]);
            }
            float m24 = mr[6].x;
            a0[24] = fmaf(xv.x, m24, a0[24]);
            a1[24] = fmaf(xv.y, m24, a1[24]);
        }
        float2* part = (float2*)lds;               // [256][25]
#pragma unroll
        for (int s = 0; s < SSZ; ++s) part[tid * SSZ + s] = make_float2(a0[s], a1[s]);
        __syncthreads();

        float2* att2 = part + 6400;                // [32][25]
        if (tid < 32) {
            float ex[SSZ], ey[SSZ];
#pragma unroll
            for (int s = 0; s < SSZ; ++s) { float v = e0[b * SSZ + s]; ex[s] = v; ey[s] = v; }
            for (int g8 = 0; g8 < 8; ++g8) {
#pragma unroll
                for (int s = 0; s < SSZ; ++s) {
                    float2 p = part[(g8 * 32 + tid) * SSZ + s];
                    ex[s] += p.x; ey[s] += p.y;
                }
            }
            float mx = ex[0], my = ey[0];
#pragma unroll
            for (int s = 1; s < SSZ; ++s) { mx = fmaxf(mx, ex[s]); my = fmaxf(my, ey[s]); }
            float sx = 0.f, sy = 0.f;
#pragma unroll
            for (int s = 0; s < SSZ; ++s) {
                ex[s] = __expf(ex[s] - mx); sx += ex[s];
                ey[s] = __expf(ey[s] - my); sy += ey[s];
            }
            float ix = 1.0f / sx, iy = 1.0f / sy;
#pragma unroll
            for (int s = 0; s < SSZ; ++s)
                att2[tid * SSZ + s] = make_float2(ex[s] * ix, ey[s] * iy);
        }
        __syncthreads();

#pragma unroll
        for (int s = 0; s < SSZ; ++s) {
            float2 av = att2[nl * SSZ + s];
            a0[s] = av.x; a1[s] = av.y;
        }
        float g = gm[0];
        float2* o2 = (float2*)(out + (size_t)b * CR * HWD);
        const int r0 = cg * 128;
        for (int r = r0; r < r0 + 128; ++r) {
            float2 xv = x2[(size_t)r * HW2 + n2c];
            const float4* vr = (const float4*)&vp[((size_t)(b << 10) + r) * SP];
            float d0 = 0.f, d1 = 0.f;
#pragma unroll
            for (int j = 0; j < 6; ++j) {
                float4 v = vr[j];
                d0 = fmaf(v.x, a0[4 * j + 0], d0);
                d0 = fmaf(v.y, a0[4 * j + 1], d0);
                d0 = fmaf(v.z, a0[4 * j + 2], d0);
                d0 = fmaf(v.w, a0[4 * j + 3], d0);
                d1 = fmaf(v.x, a1[4 * j + 0], d1);
                d1 = fmaf(v.y, a1[4 * j + 1], d1);
                d1 = fmaf(v.z, a1[4 * j + 2], d1);
                d1 = fmaf(v.w, a1[4 * j + 3], d1);
            }
            float v24 = vr[6].x;
            d0 = fmaf(v24, a0[24], d0);
            d1 = fmaf(v24, a1[24], d1);
            if (valid)
                o2[(size_t)r * HW2 + n2] =
                    make_float2(fmaf(g, d0, xv.x), fmaf(g, d1, xv.y));
        }
    }
}

extern "C" void kernel_launch(void* const* d_in, const int* in_sizes, int n_in,
                              void* d_out, int out_size, void* d_ws, size_t ws_size,
                              hipStream_t stream) {
    const float* x_rgb  = (const float*)d_in[0];
    const float* x_skel = (const float*)d_in[1];
    const float* Wq     = (const float*)d_in[2];
    const float* bq     = (const float*)d_in[3];
    const float* Wk     = (const float*)d_in[4];
    const float* bk     = (const float*)d_in[5];
    const float* Wv     = (const float*)d_in[6];
    const float* bv     = (const float*)d_in[7];
    const float* gamma  = (const float*)d_in[8];
    float* out = (float*)d_out;
    float* ws  = (float*)d_ws;

    // Zero barrier counters every replay (stream-ordered, capturable).
    hipMemsetAsync(ws + OFF_BAR, 0, BAR_UINTS * sizeof(unsigned), stream);

    hipLaunchKernelGGL(mega, dim3(NBLK), dim3(256), 0, stream,
                       x_rgb, x_skel, Wq, bq, Wk, bk, Wv, bv, gamma, out, ws);
}

// Round 5
// 287.143 us; speedup vs baseline: 2.5855x; 1.0515x over previous
//
#include <hip/hip_runtime.h>

// Problem dims (fixed by setup_inputs)
#define BB 16
#define CR 1024
#define HWD 784     // 28*28
#define HW2 392     // HWD/2 (float2 units)
#define CS 256
#define SSZ 25
#define SP 28       // padded row length for kk/M/v
#define CI 512
#define NBLK 512    // 2 blocks/CU via __launch_bounds__(256,2); LDS 54.4KB*2 fits

// Workspace layout (floats). pooled now lives in LDS only.
#define OFF_VP     102400     // [B][CR][SP] = 458752
#define OFF_MP     561152     // [B][CR][SP] = 458752
#define OFF_E0     1019904    // [B][S]      = 400
#define OFF_KK     1333904    // [B][CI][SP] = 229376
#define OFF_BAR    3842704    // barrier slots (1040 uints)

// ---- Grid barrier: relaxed-RMW tree + ONE release/acquire fence per block ----
// Proven in round 4 (256 blocks). Costs ~1 wbl2 + 1 inv per block. 512 blocks
// now; monotone counters -> rocprof-replay safe. Co-residency: exactly 2
// blocks/CU by launch bounds, so no deadlock is possible.
#define NGRP  32
#define GRPSZ 16
#define BAR_UINTS 1040  // grp[g]@g*16 (g<32), top@512, gen[g]@528+g*16

__device__ __forceinline__ void gbar(unsigned* bar, unsigned phase) {
    __syncthreads();                       // all waves' stores vmcnt-drained (in L2)
    if (threadIdx.x < 64) {
        const unsigned g = (unsigned)blockIdx.x >> 4;
        const int lane = threadIdx.x;
        unsigned tk = 0;
        if (lane == 0) {
            // flush this XCD's dirty L2 lines toward L3 BEFORE signaling arrival
            __builtin_amdgcn_fence(__ATOMIC_RELEASE, "agent");
            unsigned a = __hip_atomic_fetch_add(bar + g * 16, 1u,
                           __ATOMIC_RELAXED, __HIP_MEMORY_SCOPE_AGENT);
            if (a == phase * GRPSZ - 1)    // group complete (monotone count)
                tk = 1u + __hip_atomic_fetch_add(bar + 512, 1u,
                             __ATOMIC_RELAXED, __HIP_MEMORY_SCOPE_AGENT);
        }
        tk = __shfl(tk, 0);
        if (tk == phase * NGRP && lane < NGRP)      // last group: release all
            __hip_atomic_fetch_add(bar + 528 + lane * 16, 1u,
                                   __ATOMIC_RELAXED, __HIP_MEMORY_SCOPE_AGENT);
        if (lane == 0) {
            const unsigned* gen = bar + 528 + g * 16;
            int spins = 0;
            while (__hip_atomic_load(gen, __ATOMIC_RELAXED,
                                     __HIP_MEMORY_SCOPE_AGENT) != phase) {
                __builtin_amdgcn_s_sleep(4);
                if (++spins > (1 << 22)) break;     // safety valve
            }
            // invalidate L1/L2 before reading other XCDs' phase-N data
            __builtin_amdgcn_fence(__ATOMIC_ACQUIRE, "agent");
        }
    }
    __syncthreads();
}

// kk/v projection body (K=256); pooled[b] staged in LDS
template <int NS>
__device__ __forceinline__ void proj_body(const float* __restrict__ wrow,
                                          const float* __restrict__ pb, int s0,
                                          float bias, float* __restrict__ dst,
                                          bool zpad) {
    float acc[NS];
#pragma unroll
    for (int i = 0; i < NS; ++i) acc[i] = 0.f;
    const float4* w4 = (const float4*)wrow;
#pragma unroll 4
    for (int c4 = 0; c4 < CS / 4; ++c4) {
        float4 w = w4[c4];
        const float* p = pb + c4 * 4 * SSZ + s0;
#pragma unroll
        for (int i = 0; i < NS; ++i)
            acc[i] = fmaf(w.x, p[i],
                     fmaf(w.y, p[SSZ + i],
                     fmaf(w.z, p[2 * SSZ + i],
                     fmaf(w.w, p[3 * SSZ + i], acc[i]))));
    }
#pragma unroll
    for (int i = 0; i < NS; ++i) dst[s0 + i] = acc[i] + bias;
    if (zpad) { dst[25] = 0.f; dst[26] = 0.f; dst[27] = 0.f; }
}

__global__ __launch_bounds__(256, 2) void mega(
    const float* __restrict__ xr, const float* __restrict__ xs,
    const float* __restrict__ Wq, const float* __restrict__ bq,
    const float* __restrict__ Wk, const float* __restrict__ bk,
    const float* __restrict__ Wv, const float* __restrict__ bv,
    const float* __restrict__ gm, float* __restrict__ out,
    float* __restrict__ ws)
{
    // 54.4 KB static LDS (max = PF: part[256][25] f2 + att2[16][25] f2)
    __shared__ __align__(16) float lds[13600];

    float* vp     = ws + OFF_VP;
    float* Mp     = ws + OFF_MP;
    float* e0     = ws + OFF_E0;
    float* kk     = ws + OFF_KK;
    unsigned* bar = (unsigned*)(ws + OFF_BAR);

    const int tid  = threadIdx.x;
    const int wave = tid >> 6, lane = tid & 63;
    const int bid  = blockIdx.x;

    // ---------------- PA: pooled(LDS) -> kk = Wk*pooled+bk ; vp = Wv*pooled+bv --
    // 16 b x 32 slots; slots 0..23 are the proven (rb,sh) projection tasks.
    // pooled[b][c][s] = mean_w x_skel[b,c,s,w], computed block-locally into LDS
    // (fuses old P1, removing one grid barrier).
    {
        int b = bid >> 5, slot = bid & 31;
        if (slot < 24) {
            const float* xsb = xs + (size_t)b * CS * SSZ * SSZ;
#pragma unroll
            for (int q = 0; q < 25; ++q) {
                int e = tid + 256 * q;             // e = c*25+s, 0..6399
                const float* row = xsb + (size_t)e * SSZ;
                float s = 0.f;
#pragma unroll
                for (int w = 0; w < SSZ; ++w) s += row[w];
                lds[e] = s * (1.0f / SSZ);
            }
            __syncthreads();
            int rb = slot >> 2, sh = slot & 3;
            const float* wrow; float bias; float* dst;
            if (rb < 2) {
                int i = rb * 256 + tid;
                wrow = Wk + (size_t)i * CS; bias = bk[i];
                dst  = kk + ((size_t)b * CI + i) * SP;
            } else {
                int r = (rb - 2) * 256 + tid;
                wrow = Wv + (size_t)r * CS; bias = bv[r];
                dst  = vp + ((size_t)b * CR + r) * SP;
            }
            int s0 = sh * 7;
            if (sh < 3) proj_body<7>(wrow, lds, s0, bias, dst, false);
            else        proj_body<4>(wrow, lds, s0, bias, dst, true);
        }
    }
    gbar(bar, 1);

    // ---------------- PB: Mp (K=512 direct) + e0 --------------------------------
    // 416 blocks: 13 s-chunks(2 cols) x 16 b x 2 c-halves; in-block K-split by 2.
    // Blocks 448..511: e0[b,s] = sum_i bq[i]*kk[b,i,s] (400 wave-tasks).
    if (bid < 416) {
        int sc = bid % 13, rem = bid / 13;
        int b = rem >> 1, chalf = rem & 1;
        int s0 = sc * 2;
        float* kst = lds;                  // [512][2] = 1024 floats
        float* red = lds + 1024;           // [128][9] padded = 1152 floats
        const float* kkb = kk + (size_t)b * CI * SP;
#pragma unroll
        for (int q = 0; q < 4; ++q) {
            int d = tid + 256 * q;         // i = d>>1, col = d&1
            kst[d] = kkb[(size_t)(d >> 1) * SP + s0 + (d & 1)];
        }
        __syncthreads();
        int half = tid >> 7, tq = tid & 127;
        int cq = chalf * 512 + 4 * tq;     // 4 consecutive c columns
        float acc[8];                      // [4c][2s]
#pragma unroll
        for (int e = 0; e < 8; ++e) acc[e] = 0.f;
        const float2* kst2 = (const float2*)kst;
        int i0 = half * 256;
#pragma unroll 4
        for (int i = 0; i < 256; ++i) {
            float4 w = *(const float4*)(Wq + (size_t)(i0 + i) * CR + cq);
            float2 k = kst2[i0 + i];
#pragma unroll
            for (int cl = 0; cl < 4; ++cl) {
                float wc = cl == 0 ? w.x : cl == 1 ? w.y : cl == 2 ? w.z : w.w;
                acc[cl * 2 + 0] = fmaf(wc, k.x, acc[cl * 2 + 0]);
                acc[cl * 2 + 1] = fmaf(wc, k.y, acc[cl * 2 + 1]);
            }
        }
        if (half == 1) {
#pragma unroll
            for (int j = 0; j < 8; ++j) red[tq * 9 + j] = acc[j];
        }
        __syncthreads();
        if (half == 0) {
#pragma unroll
            for (int j = 0; j < 8; ++j) acc[j] += red[tq * 9 + j];
#pragma unroll
            for (int cl = 0; cl < 4; ++cl) {
                float2 o = make_float2(acc[cl * 2 + 0], acc[cl * 2 + 1]);
                *(float2*)&Mp[((size_t)(b << 10) + cq + cl) * SP + s0] = o;
            }
        }
    } else if (bid >= 448) {
        int wt0 = (bid - 448) * 4 + wave;  // 256 wave-slots for 400 (b,s) tasks
        for (int wt = wt0; wt < 400; wt += 256) {
            int s = wt % 25, b = wt / 25;
            const float* kb = kk + (size_t)b * CI * SP;
            float a = 0.f;
#pragma unroll
            for (int k = 0; k < CI / 64; ++k) {
                int i = lane + 64 * k;
                a = fmaf(bq[i], kb[(size_t)i * SP + s], a);
            }
#pragma unroll
            for (int off = 32; off > 0; off >>= 1) a += __shfl_down(a, off);
            if (lane == 0) e0[b * SSZ + s] = a;
        }
    }
    gbar(bar, 2);

    // ---------------- PF: energy + softmax + out, fused per (b, n-tile) --------
    // 400 blocks = 16 b x 25 tiles of 16 float2-lanes. cg=tid>>4 (16 groups of
    // 64 c/r-rows), nl=tid&15. Energy partials in regs -> LDS reduce -> softmax
    // by 16 lanes -> out pass over the same 64 rows (x_rgb L1-warm).
    if (bid < 25 * BB) {
        int tile = bid % 25, b = bid / 25;
        int cg = tid >> 4, nl = tid & 15;
        int n2 = tile * 16 + nl;
        bool valid = n2 < HW2;
        int n2c = valid ? n2 : 0;
        const float2* x2 = (const float2*)(xr + (size_t)b * CR * HWD);

        float a0[SSZ], a1[SSZ];
#pragma unroll
        for (int s = 0; s < SSZ; ++s) { a0[s] = 0.f; a1[s] = 0.f; }
        const int c0 = cg * 64;
        for (int c = c0; c < c0 + 64; c += 4) {
            float2 xv[4];
#pragma unroll
            for (int u = 0; u < 4; ++u)
                xv[u] = x2[(size_t)(c + u) * HW2 + n2c];
#pragma unroll
            for (int u = 0; u < 4; ++u) {
                const float4* mr = (const float4*)&Mp[((size_t)(b << 10) + c + u) * SP];
#pragma unroll
                for (int j = 0; j < 6; ++j) {
                    float4 m = mr[j];
                    a0[4 * j + 0] = fmaf(xv[u].x, m.x, a0[4 * j + 0]);
                    a0[4 * j + 1] = fmaf(xv[u].x, m.y, a0[4 * j + 1]);
                    a0[4 * j + 2] = fmaf(xv[u].x, m.z, a0[4 * j + 2]);
                    a0[4 * j + 3] = fmaf(xv[u].x, m.w, a0[4 * j + 3]);
                    a1[4 * j + 0] = fmaf(xv[u].y, m.x, a1[4 * j + 0]);
                    a1[4 * j + 1] = fmaf(xv[u].y, m.y, a1[4 * j + 1]);
                    a1[4 * j + 2] = fmaf(xv[u].y, m.z, a1[4 * j + 2]);
                    a1[4 * j + 3] = fmaf(xv[u].y, m.w, a1[4 * j + 3]);
                }
                float m24 = mr[6].x;
                a0[24] = fmaf(xv[u].x, m24, a0[24]);
                a1[24] = fmaf(xv[u].y, m24, a1[24]);
            }
        }
        float2* part = (float2*)lds;               // [256][25]
#pragma unroll
        for (int s = 0; s < SSZ; ++s) part[tid * SSZ + s] = make_float2(a0[s], a1[s]);
        __syncthreads();

        float2* att2 = part + 6400;                // [16][25]
        if (tid < 16) {
            float ex[SSZ], ey[SSZ];
#pragma unroll
            for (int s = 0; s < SSZ; ++s) { float v = e0[b * SSZ + s]; ex[s] = v; ey[s] = v; }
            for (int g16 = 0; g16 < 16; ++g16) {
#pragma unroll
                for (int s = 0; s < SSZ; ++s) {
                    float2 p = part[(g16 * 16 + tid) * SSZ + s];
                    ex[s] += p.x; ey[s] += p.y;
                }
            }
            float mx = ex[0], my = ey[0];
#pragma unroll
            for (int s = 1; s < SSZ; ++s) { mx = fmaxf(mx, ex[s]); my = fmaxf(my, ey[s]); }
            float sx = 0.f, sy = 0.f;
#pragma unroll
            for (int s = 0; s < SSZ; ++s) {
                ex[s] = __expf(ex[s] - mx); sx += ex[s];
                ey[s] = __expf(ey[s] - my); sy += ey[s];
            }
            float ix = 1.0f / sx, iy = 1.0f / sy;
#pragma unroll
            for (int s = 0; s < SSZ; ++s)
                att2[tid * SSZ + s] = make_float2(ex[s] * ix, ey[s] * iy);
        }
        __syncthreads();

#pragma unroll
        for (int s = 0; s < SSZ; ++s) {
            float2 av = att2[nl * SSZ + s];
            a0[s] = av.x; a1[s] = av.y;
        }
        float g = gm[0];
        float2* o2 = (float2*)(out + (size_t)b * CR * HWD);
        const int r0 = cg * 64;
        for (int r = r0; r < r0 + 64; r += 2) {
            float2 xva = x2[(size_t)r * HW2 + n2c];
            float2 xvb = x2[(size_t)(r + 1) * HW2 + n2c];
            const float4* vra = (const float4*)&vp[((size_t)(b << 10) + r) * SP];
            const float4* vrb = (const float4*)&vp[((size_t)(b << 10) + r + 1) * SP];
            float d0a = 0.f, d1a = 0.f, d0b = 0.f, d1b = 0.f;
#pragma unroll
            for (int j = 0; j < 6; ++j) {
                float4 va = vra[j], vb = vrb[j];
                d0a = fmaf(va.x, a0[4 * j + 0], d0a);
                d0a = fmaf(va.y, a0[4 * j + 1], d0a);
                d0a = fmaf(va.z, a0[4 * j + 2], d0a);
                d0a = fmaf(va.w, a0[4 * j + 3], d0a);
                d1a = fmaf(va.x, a1[4 * j + 0], d1a);
                d1a = fmaf(va.y, a1[4 * j + 1], d1a);
                d1a = fmaf(va.z, a1[4 * j + 2], d1a);
                d1a = fmaf(va.w, a1[4 * j + 3], d1a);
                d0b = fmaf(vb.x, a0[4 * j + 0], d0b);
                d0b = fmaf(vb.y, a0[4 * j + 1], d0b);
                d0b = fmaf(vb.z, a0[4 * j + 2], d0b);
                d0b = fmaf(vb.w, a0[4 * j + 3], d0b);
                d1b = fmaf(vb.x, a1[4 * j + 0], d1b);
                d1b = fmaf(vb.y, a1[4 * j + 1], d1b);
                d1b = fmaf(vb.z, a1[4 * j + 2], d1b);
                d1b = fmaf(vb.w, a1[4 * j + 3], d1b);
            }
            d0a = fmaf(vra[6].x, a0[24], d0a);
            d1a = fmaf(vra[6].x, a1[24], d1a);
            d0b = fmaf(vrb[6].x, a0[24], d0b);
            d1b = fmaf(vrb[6].x, a1[24], d1b);
            if (valid) {
                o2[(size_t)r * HW2 + n2] =
                    make_float2(fmaf(g, d0a, xva.x), fmaf(g, d1a, xva.y));
                o2[(size_t)(r + 1) * HW2 + n2] =
                    make_float2(fmaf(g, d0b, xvb.x), fmaf(g, d1b, xvb.y));
            }
        }
    }
}

extern "C" void kernel_launch(void* const* d_in, const int* in_sizes, int n_in,
                              void* d_out, int out_size, void* d_ws, size_t ws_size,
                              hipStream_t stream) {
    const float* x_rgb  = (const float*)d_in[0];
    const float* x_skel = (const float*)d_in[1];
    const float* Wq     = (const float*)d_in[2];
    const float* bq     = (const float*)d_in[3];
    const float* Wk     = (const float*)d_in[4];
    const float* bk     = (const float*)d_in[5];
    const float* Wv     = (const float*)d_in[6];
    const float* bv     = (const float*)d_in[7];
    const float* gamma  = (const float*)d_in[8];
    float* out = (float*)d_out;
    float* ws  = (float*)d_ws;

    // Zero barrier counters every replay (stream-ordered, capturable).
    hipMemsetAsync(ws + OFF_BAR, 0, BAR_UINTS * sizeof(unsigned), stream);

    hipLaunchKernelGGL(mega, dim3(NBLK), dim3(256), 0, stream,
                       x_rgb, x_skel, Wq, bq, Wk, bk, Wv, bv, gamma, out, ws);
}

// Round 6
// 264.553 us; speedup vs baseline: 2.8063x; 1.0854x over previous
//
#include <hip/hip_runtime.h>

// Problem dims (fixed by setup_inputs)
#define BB 16
#define CR 1024
#define HWD 784     // 28*28
#define HW2 392     // HWD/2 (float2 units)
#define CS 256
#define SSZ 25
#define SP 28       // padded row length for kk/M/v
#define CI 512
#define NBLK 512    // 2 blocks/CU via __launch_bounds__(256,2): 512 slots = 512 blocks
                    // -> all co-resident (proven r1-r5) and 64 blocks per XCD.

// Workspace layout (floats)
#define OFF_VP     102400     // [B][CR][SP] = 458752
#define OFF_MP     561152     // [B][CR][SP] = 458752
#define OFF_E0     1019904    // [B][S]      = 400
#define OFF_KK     1333904    // [B][CI][SP] = 229376
#define OFF_CTR    2000000    // counters: 88 x 64B slots = 5632 B (inside old Ep region)
#define CTR_UINTS  (88 * 16)

// Counter slots (each on its own 64B line):
//   xcdCnt[x] = slot x (x<8) ; taskA[b]=8+b ; doneA[b]=24+b ;
//   taskB[b]=40+b ; doneB[b]=56+b ; taskF[b]=72+b
// All flag traffic is agent-scope relaxed RMW (the one op class proven
// coherent in r1/r2/r4); every (taskX[b], doneX[b]) is touched ONLY by the
// XCD that owns b, and all DATA producer->consumer pairs are same-XCD, so
// plain cached stores/loads meet in the local L2 — NO fences anywhere.
// Deterministic recompute per launch makes any residual L1 reuse value-safe.

__device__ __forceinline__ unsigned rmw_inc(unsigned* p) {
    return __hip_atomic_fetch_add(p, 1u, __ATOMIC_RELAXED, __HIP_MEMORY_SCOPE_AGENT);
}
__device__ __forceinline__ unsigned aload(const unsigned* p) {
    return __hip_atomic_load(p, __ATOMIC_RELAXED, __HIP_MEMORY_SCOPE_AGENT);
}

// kk/v projection body (K=256); pooled[b] staged in LDS
template <int NS>
__device__ __forceinline__ void proj_body(const float* __restrict__ wrow,
                                          const float* __restrict__ pb, int s0,
                                          float bias, float* __restrict__ dst,
                                          bool zpad) {
    float acc[NS];
#pragma unroll
    for (int i = 0; i < NS; ++i) acc[i] = 0.f;
    const float4* w4 = (const float4*)wrow;
#pragma unroll 4
    for (int c4 = 0; c4 < CS / 4; ++c4) {
        float4 w = w4[c4];
        const float* p = pb + c4 * 4 * SSZ + s0;
#pragma unroll
        for (int i = 0; i < NS; ++i)
            acc[i] = fmaf(w.x, p[i],
                     fmaf(w.y, p[SSZ + i],
                     fmaf(w.z, p[2 * SSZ + i],
                     fmaf(w.w, p[3 * SSZ + i], acc[i]))));
    }
#pragma unroll
    for (int i = 0; i < NS; ++i) dst[s0 + i] = acc[i] + bias;
    if (zpad) { dst[25] = 0.f; dst[26] = 0.f; dst[27] = 0.f; }
}

__global__ __launch_bounds__(256, 2) void mega(
    const float* __restrict__ xr, const float* __restrict__ xs,
    const float* __restrict__ Wq, const float* __restrict__ bq,
    const float* __restrict__ Wk, const float* __restrict__ bk,
    const float* __restrict__ Wv, const float* __restrict__ bv,
    const float* __restrict__ gm, float* __restrict__ out,
    float* __restrict__ ws)
{
    __shared__ __align__(16) float lds[13600];     // 54.4 KB; 2 blocks/CU
    __shared__ unsigned comm;

    float* vp     = ws + OFF_VP;
    float* Mp     = ws + OFF_MP;
    float* e0     = ws + OFF_E0;
    float* kk     = ws + OFF_KK;
    unsigned* ctr = (unsigned*)(ws + OFF_CTR);

    const int tid  = threadIdx.x;
    const int wave = tid >> 6, lane = tid & 63;

    // Which XCD am I on? HW_REG_XCC_ID = hwreg 20, offset 0, size 4.
    const unsigned xcc = __builtin_amdgcn_s_getreg(20 | (0 << 6) | (3 << 11)) & 7u;

    if (tid == 0) comm = rmw_inc(ctr + xcc * 16);  // gang registration -> rank
    __syncthreads();
    const unsigned pref = comm & 1u;               // split gang across its 2 batches

    for (int pass = 0; pass < 2; ++pass) {
        const int b = 2 * (int)xcc + (int)(pref ^ (unsigned)pass);
        unsigned* tA = ctr + (8  + b) * 16;
        unsigned* dA = ctr + (24 + b) * 16;
        unsigned* tB = ctr + (40 + b) * 16;
        unsigned* dB = ctr + (56 + b) * 16;
        unsigned* tF = ctr + (72 + b) * 16;

        // ---------------- PA: pooled(LDS) -> kk/vp projections (24 tasks) ------
        for (;;) {
            __syncthreads();
            if (tid == 0) comm = rmw_inc(tA);
            __syncthreads();
            unsigned t = comm;
            if (t >= 24) break;
            const float* xsb = xs + (size_t)b * CS * SSZ * SSZ;
#pragma unroll
            for (int q = 0; q < 25; ++q) {
                int e = tid + 256 * q;             // e = c*25+s
                const float* row = xsb + (size_t)e * SSZ;
                float s = 0.f;
#pragma unroll
                for (int w = 0; w < SSZ; ++w) s += row[w];
                lds[e] = s * (1.0f / SSZ);
            }
            __syncthreads();
            int rb = (int)t >> 2, sh = (int)t & 3;
            const float* wrow; float bias; float* dst;
            if (rb < 2) {
                int i = rb * 256 + tid;
                wrow = Wk + (size_t)i * CS; bias = bk[i];
                dst  = kk + ((size_t)b * CI + i) * SP;
            } else {
                int r = (rb - 2) * 256 + tid;
                wrow = Wv + (size_t)r * CS; bias = bv[r];
                dst  = vp + ((size_t)b * CR + r) * SP;
            }
            int s0 = sh * 7;
            if (sh < 3) proj_body<7>(wrow, lds, s0, bias, dst, false);
            else        proj_body<4>(wrow, lds, s0, bias, dst, true);
            __syncthreads();                       // vmcnt-drain: stores in L2
            if (tid == 0) rmw_inc(dA);
        }
        // gate A
        __syncthreads();
        if (tid == 0) {
            int spins = 0;
            while (aload(dA) < 24u) {
                __builtin_amdgcn_s_sleep(8);
                if (++spins > (1 << 18)) break;    // safety valve
            }
        }
        __syncthreads();

        // ---------------- PB: Mp (14 tasks, K=512) + e0 (task 14) --------------
        for (;;) {
            __syncthreads();
            if (tid == 0) comm = rmw_inc(tB);
            __syncthreads();
            unsigned t = comm;
            if (t >= 15) break;
            if (t < 14) {
                int sc = (int)t % 7, chalf = (int)t / 7;
                int s0 = sc * 4;
                float* kst = lds;                  // [512][4] = 2048
                float* red = lds + 2048;           // [128][17] = 2176
                const float* kkb = kk + (size_t)b * CI * SP;
#pragma unroll
                for (int q = 0; q < 8; ++q) {
                    int d = tid + 256 * q;         // i=d>>2, col=d&3
                    kst[d] = kkb[(size_t)(d >> 2) * SP + s0 + (d & 3)];
                }
                __syncthreads();
                int half = tid >> 7, tq = tid & 127;
                int cq = chalf * 512 + 4 * tq;
                float acc[16];
#pragma unroll
                for (int e = 0; e < 16; ++e) acc[e] = 0.f;
                const float4* kst4 = (const float4*)kst;
                int i0 = half * 256;
#pragma unroll 4
                for (int i = 0; i < 256; ++i) {
                    float4 w = *(const float4*)(Wq + (size_t)(i0 + i) * CR + cq);
                    float4 k = kst4[i0 + i];
#pragma unroll
                    for (int cl = 0; cl < 4; ++cl) {
                        float wc = cl == 0 ? w.x : cl == 1 ? w.y : cl == 2 ? w.z : w.w;
                        acc[cl * 4 + 0] = fmaf(wc, k.x, acc[cl * 4 + 0]);
                        acc[cl * 4 + 1] = fmaf(wc, k.y, acc[cl * 4 + 1]);
                        acc[cl * 4 + 2] = fmaf(wc, k.z, acc[cl * 4 + 2]);
                        acc[cl * 4 + 3] = fmaf(wc, k.w, acc[cl * 4 + 3]);
                    }
                }
                if (half == 1) {
#pragma unroll
                    for (int j = 0; j < 16; ++j) red[tq * 17 + j] = acc[j];
                }
                __syncthreads();
                if (half == 0) {
#pragma unroll
                    for (int j = 0; j < 16; ++j) acc[j] += red[tq * 17 + j];
#pragma unroll
                    for (int cl = 0; cl < 4; ++cl) {
                        float4 o;
                        o.x = acc[cl * 4 + 0]; o.y = acc[cl * 4 + 1];
                        o.z = acc[cl * 4 + 2]; o.w = acc[cl * 4 + 3];
                        *(float4*)&Mp[((size_t)(b << 10) + cq + cl) * SP + s0] = o;
                    }
                }
            } else {
                // e0[b][s] = sum_i bq[i]*kk[b][i][s]; waves split s
                const float* kb = kk + (size_t)b * CI * SP;
                for (int s = wave; s < SSZ; s += 4) {
                    float a = 0.f;
#pragma unroll
                    for (int k2 = 0; k2 < CI / 64; ++k2) {
                        int i = lane + 64 * k2;
                        a = fmaf(bq[i], kb[(size_t)i * SP + s], a);
                    }
#pragma unroll
                    for (int off = 32; off > 0; off >>= 1) a += __shfl_down(a, off);
                    if (lane == 0) e0[b * SSZ + s] = a;
                }
            }
            __syncthreads();                       // vmcnt-drain
            if (tid == 0) rmw_inc(dB);
        }
        // gate B
        __syncthreads();
        if (tid == 0) {
            int spins = 0;
            while (aload(dB) < 15u) {
                __builtin_amdgcn_s_sleep(8);
                if (++spins > (1 << 18)) break;    // safety valve
            }
        }
        __syncthreads();

        // ---------------- PF: energy + softmax + out (25 tile-tasks) -----------
        for (;;) {
            __syncthreads();
            if (tid == 0) comm = rmw_inc(tF);
            __syncthreads();
            unsigned t = comm;
            if (t >= 25) break;
            int cg = tid >> 4, nl = tid & 15;
            int n2 = (int)t * 16 + nl;
            bool valid = n2 < HW2;
            int n2c = valid ? n2 : 0;
            const float2* x2 = (const float2*)(xr + (size_t)b * CR * HWD);

            float a0[SSZ], a1[SSZ];
#pragma unroll
            for (int s = 0; s < SSZ; ++s) { a0[s] = 0.f; a1[s] = 0.f; }
            const int c0 = cg * 64;
            for (int c = c0; c < c0 + 64; c += 4) {
                float2 xv[4];
#pragma unroll
                for (int u = 0; u < 4; ++u)
                    xv[u] = x2[(size_t)(c + u) * HW2 + n2c];
#pragma unroll
                for (int u = 0; u < 4; ++u) {
                    const float4* mr = (const float4*)&Mp[((size_t)(b << 10) + c + u) * SP];
#pragma unroll
                    for (int j = 0; j < 6; ++j) {
                        float4 m = mr[j];
                        a0[4 * j + 0] = fmaf(xv[u].x, m.x, a0[4 * j + 0]);
                        a0[4 * j + 1] = fmaf(xv[u].x, m.y, a0[4 * j + 1]);
                        a0[4 * j + 2] = fmaf(xv[u].x, m.z, a0[4 * j + 2]);
                        a0[4 * j + 3] = fmaf(xv[u].x, m.w, a0[4 * j + 3]);
                        a1[4 * j + 0] = fmaf(xv[u].y, m.x, a1[4 * j + 0]);
                        a1[4 * j + 1] = fmaf(xv[u].y, m.y, a1[4 * j + 1]);
                        a1[4 * j + 2] = fmaf(xv[u].y, m.z, a1[4 * j + 2]);
                        a1[4 * j + 3] = fmaf(xv[u].y, m.w, a1[4 * j + 3]);
                    }
                    float m24 = mr[6].x;
                    a0[24] = fmaf(xv[u].x, m24, a0[24]);
                    a1[24] = fmaf(xv[u].y, m24, a1[24]);
                }
            }
            float2* part = (float2*)lds;           // [256][25]
#pragma unroll
            for (int s = 0; s < SSZ; ++s) part[tid * SSZ + s] = make_float2(a0[s], a1[s]);
            __syncthreads();

            float2* att2 = part + 6400;            // [16][25]
            if (tid < 16) {
                float ex[SSZ], ey[SSZ];
#pragma unroll
                for (int s = 0; s < SSZ; ++s) { float v = e0[b * SSZ + s]; ex[s] = v; ey[s] = v; }
                for (int g16 = 0; g16 < 16; ++g16) {
#pragma unroll
                    for (int s = 0; s < SSZ; ++s) {
                        float2 p = part[(g16 * 16 + tid) * SSZ + s];
                        ex[s] += p.x; ey[s] += p.y;
                    }
                }
                float mx = ex[0], my = ey[0];
#pragma unroll
                for (int s = 1; s < SSZ; ++s) { mx = fmaxf(mx, ex[s]); my = fmaxf(my, ey[s]); }
                float sx = 0.f, sy = 0.f;
#pragma unroll
                for (int s = 0; s < SSZ; ++s) {
                    ex[s] = __expf(ex[s] - mx); sx += ex[s];
                    ey[s] = __expf(ey[s] - my); sy += ey[s];
                }
                float ix = 1.0f / sx, iy = 1.0f / sy;
#pragma unroll
                for (int s = 0; s < SSZ; ++s)
                    att2[tid * SSZ + s] = make_float2(ex[s] * ix, ey[s] * iy);
            }
            __syncthreads();

#pragma unroll
            for (int s = 0; s < SSZ; ++s) {
                float2 av = att2[nl * SSZ + s];
                a0[s] = av.x; a1[s] = av.y;
            }
            float g = gm[0];
            float2* o2 = (float2*)(out + (size_t)b * CR * HWD);
            const int r0 = cg * 64;
            for (int r = r0; r < r0 + 64; r += 2) {
                float2 xva = x2[(size_t)r * HW2 + n2c];
                float2 xvb = x2[(size_t)(r + 1) * HW2 + n2c];
                const float4* vra = (const float4*)&vp[((size_t)(b << 10) + r) * SP];
                const float4* vrb = (const float4*)&vp[((size_t)(b << 10) + r + 1) * SP];
                float d0a = 0.f, d1a = 0.f, d0b = 0.f, d1b = 0.f;
#pragma unroll
                for (int j = 0; j < 6; ++j) {
                    float4 va = vra[j], vb = vrb[j];
                    d0a = fmaf(va.x, a0[4 * j + 0], d0a);
                    d0a = fmaf(va.y, a0[4 * j + 1], d0a);
                    d0a = fmaf(va.z, a0[4 * j + 2], d0a);
                    d0a = fmaf(va.w, a0[4 * j + 3], d0a);
                    d1a = fmaf(va.x, a1[4 * j + 0], d1a);
                    d1a = fmaf(va.y, a1[4 * j + 1], d1a);
                    d1a = fmaf(va.z, a1[4 * j + 2], d1a);
                    d1a = fmaf(va.w, a1[4 * j + 3], d1a);
                    d0b = fmaf(vb.x, a0[4 * j + 0], d0b);
                    d0b = fmaf(vb.y, a0[4 * j + 1], d0b);
                    d0b = fmaf(vb.z, a0[4 * j + 2], d0b);
                    d0b = fmaf(vb.w, a0[4 * j + 3], d0b);
                    d1b = fmaf(vb.x, a1[4 * j + 0], d1b);
                    d1b = fmaf(vb.y, a1[4 * j + 1], d1b);
                    d1b = fmaf(vb.z, a1[4 * j + 2], d1b);
                    d1b = fmaf(vb.w, a1[4 * j + 3], d1b);
                }
                d0a = fmaf(vra[6].x, a0[24], d0a);
                d1a = fmaf(vra[6].x, a1[24], d1a);
                d0b = fmaf(vrb[6].x, a0[24], d0b);
                d1b = fmaf(vrb[6].x, a1[24], d1b);
                if (valid) {
                    o2[(size_t)r * HW2 + n2] =
                        make_float2(fmaf(g, d0a, xva.x), fmaf(g, d1a, xva.y));
                    o2[(size_t)(r + 1) * HW2 + n2] =
                        make_float2(fmaf(g, d0b, xvb.x), fmaf(g, d1b, xvb.y));
                }
            }
        }
    }
}

extern "C" void kernel_launch(void* const* d_in, const int* in_sizes, int n_in,
                              void* d_out, int out_size, void* d_ws, size_t ws_size,
                              hipStream_t stream) {
    const float* x_rgb  = (const float*)d_in[0];
    const float* x_skel = (const float*)d_in[1];
    const float* Wq     = (const float*)d_in[2];
    const float* bq     = (const float*)d_in[3];
    const float* Wk     = (const float*)d_in[4];
    const float* bk     = (const float*)d_in[5];
    const float* Wv     = (const float*)d_in[6];
    const float* bv     = (const float*)d_in[7];
    const float* gamma  = (const float*)d_in[8];
    float* out = (float*)d_out;
    float* ws  = (float*)d_ws;

    // Zero all task/done/gang counters every replay (stream-ordered, capturable).
    hipMemsetAsync(ws + OFF_CTR, 0, CTR_UINTS * sizeof(unsigned), stream);

    hipLaunchKernelGGL(mega, dim3(NBLK), dim3(256), 0, stream,
                       x_rgb, x_skel, Wq, bq, Wk, bk, Wv, bv, gamma, out, ws);
}